// Round 5
// baseline (372.809 us; speedup 1.0000x reference)
//
#include <hip/hip_runtime.h>

// CRF forward: B=512, T=1024, N=64. fwd/bwd split, one wave per chain.
// Round 15: ALL-VALU step. Round-14 post-mortem: E finally resident
// (VGPR 88 = 64 E + 24 working) yet 217us unchanged -> at 1 wave/SIMD the
// step cost IS the dependent chain, and round 14's chain was dominated by
// (a) 4 asm-VOLATILE xsum32 blocks (volatile => strictly ordered),
// (b) a ~120cyc ds_swizzle round-trip, (c) a depth-4 DPP ladder.
// Fixes: depth-2 DPP ladder (all 16 xor masks direct: quad_perm for 1-3,
// half_mirror-composites for 4-7, row_ror:8-composites for 8-15);
// bit-4 reduce via v_permlane16_swap_b32 (gfx950; row-pair swap + add =
// xor16 pair-sum, order-robust like the proven permlane32 trick); asm
// blocks non-volatile so the 4 group-reduces interleave. Per-step DS: 0.
// Chain ~80cyc, issue ~76 VALU; predicted ~170 cyc/step.
// Math (verified absmax 0.0 rounds 10/12/13/14): exp-domain recurrence
//   a'_j = (sum_i a_i E_ij) * w_j, exponent-only rescale every 4 steps,
//   out = ln2 * (off_f + off_b + log2(sum_i a_i b_i)).

typedef float f2 __attribute__((ext_vector_type(2)));
typedef float f4 __attribute__((ext_vector_type(4)));

constexpr int Tt = 1024;
constexpr int Nn = 64;
constexpr int ES  = 68;  // Erow stride (floats)
constexpr int EPS = 68;  // Eperm per-thread stride (floats), 272B
constexpr float LN2 = 0.69314718055994530942f;

template<int CTRL>
__device__ __forceinline__ float dppf(float x) {
    return __uint_as_float((unsigned)__builtin_amdgcn_update_dpp(
        0, (int)__float_as_uint(x), CTRL, 0xF, 0xF, false));
}

// Pair-sum across the 32-lane halves (bit 5), order-robust: swap with a
// copy, add both outputs. s_nop 1 guards the VALU-write -> cross-lane-read
// hazard. NON-volatile: pure value op, let the scheduler interleave.
__device__ __forceinline__ float xsum32(float x) {
    float a = x, b = x;
    asm("s_nop 1\n\tv_permlane32_swap_b32 %0, %1" : "+v"(a), "+v"(b));
    return a + b;
}

// Pair-sum across 16-lane row pairs (bit 4), same order-robust pattern:
// v_permlane16_swap_b32 swaps 16-lane rows between the two operands;
// whichever orientation, {a,b} together hold each row once -> a+b is the
// xor16 pair-sum replicated.
__device__ __forceinline__ float xsum16(float x) {
    float a = x, b = x;
    asm("s_nop 1\n\tv_permlane16_swap_b32 %0, %1" : "+v"(a), "+v"(b));
    return a + b;
}

__global__ __launch_bounds__(128, 1) void crf_fwd(
    const float* __restrict__ unary,
    const int*   __restrict__ lengths,
    const float* __restrict__ trans,
    float*       __restrict__ out)
{
    const int b    = blockIdx.x;
    const int tid  = threadIdx.x;
    const int w    = tid >> 6;   // 0 = forward wave, 1 = backward wave
    const int lane = tid & 63;
    const int p    = lane & 15;
    const int r    = lane >> 4;

    __shared__ float Erow[Nn * ES];     // Erow[i*ES+j] = exp(trans[i][j])
    __shared__ float Eperm[128 * EPS];  // per-thread E in gather order
    __shared__ float shb[Nn];           // beta at midpoint (combine)
    __shared__ int   sh_off_b;          // bwd exponent offset

    // Phase 1: stage E = exp(trans) row-major (coalesced global reads).
    #pragma unroll
    for (int c = 0; c < (Nn * Nn) / 128; ++c) {
        int idx = c * 128 + tid;
        Erow[(idx >> 6) * ES + (idx & 63)] = __expf(trans[idx]);
    }
    __syncthreads();

    // Phase 2: write this thread's 64 E values in gather order. The new
    // DPP ladder realizes EVERY xor mask s directly, so s_m = m:
    //   v = g*16 + s,  i = 16r + (p^s),  o = p + 16g
    //   fwd uses M[o][i] = E[i][o] (a' = E^T a); bwd M[o][i] = E[o][i].
    float* ep = &Eperm[tid * EPS];
    #pragma unroll
    for (int v = 0; v < 64; ++v) {
        int g = v >> 4, s = v & 15;
        int i = 16 * r + (p ^ s);
        int o = p + 16 * g;
        ep[v] = (w == 0) ? Erow[i * ES + o] : Erow[o * ES + i];
    }
    // Same-thread DS write->read is in-order; no barrier needed.

    // Phase 3: contiguous f4 loads into NAMED registers (the pattern
    // proven register-resident in rounds 10/11/14), then pin.
    const f4* eb = (const f4*)ep;
    f4 EA0  = eb[0],  EA1  = eb[1],  EA2  = eb[2],  EA3  = eb[3];
    f4 EA4  = eb[4],  EA5  = eb[5],  EA6  = eb[6],  EA7  = eb[7];
    f4 EA8  = eb[8],  EA9  = eb[9],  EA10 = eb[10], EA11 = eb[11];
    f4 EA12 = eb[12], EA13 = eb[13], EA14 = eb[14], EA15 = eb[15];
    asm volatile("" : "+v"(EA0),  "+v"(EA1),  "+v"(EA2),  "+v"(EA3),
                      "+v"(EA4),  "+v"(EA5),  "+v"(EA6),  "+v"(EA7),
                      "+v"(EA8),  "+v"(EA9),  "+v"(EA10), "+v"(EA11),
                      "+v"(EA12), "+v"(EA13), "+v"(EA14), "+v"(EA15));

    int L = lengths[b];
    L = L < 1 ? 1 : (L > Tt ? Tt : L);
    const int m2 = (L - 1) >> 1;

    const float* ub = unary + (size_t)b * Tt * Nn;

    const int trips = (w == 0) ? m2 : (L - 1 - m2);
    const int tbase = (w == 0) ? 1 : (L - 1);
    const int dir   = (w == 0) ? 1 : -1;

    // Exp-domain state + exponent offset.
    float acc = (w == 0) ? __expf(ub[lane]) : 1.0f;
    int   off = 0;

    // 8-step lookahead: wq = exp'd w for steps s0..s0+3,
    //                   uq = raw u for steps s0+4..s0+7.
    const int smax = trips > 0 ? trips - 1 : 0;
    float wq0, wq1, wq2, wq3, uq0, uq1, uq2, uq3;
    {
        int c0 = 0 < smax ? 0 : smax, c1 = 1 < smax ? 1 : smax;
        int c2 = 2 < smax ? 2 : smax, c3 = 3 < smax ? 3 : smax;
        wq0 = __expf(ub[(tbase + dir * c0) * Nn + lane]);
        wq1 = __expf(ub[(tbase + dir * c1) * Nn + lane]);
        wq2 = __expf(ub[(tbase + dir * c2) * Nn + lane]);
        wq3 = __expf(ub[(tbase + dir * c3) * Nn + lane]);
        int c4 = 4 < smax ? 4 : smax, c5 = 5 < smax ? 5 : smax;
        int c6 = 6 < smax ? 6 : smax, c7 = 7 < smax ? 7 : smax;
        uq0 = ub[(tbase + dir * c4) * Nn + lane];
        uq1 = ub[(tbase + dir * c5) * Nn + lane];
        uq2 = ub[(tbase + dir * c6) * Nn + lane];
        uq3 = ub[(tbase + dir * c7) * Nn + lane];
    }

    for (int s0 = 0; s0 < trips; s0 += 4) {
        // Issue raw loads 8 ahead; exp the 4-ahead batch. Both off-chain.
        float un0, un1, un2, un3, wn0, wn1, wn2, wn3;
        {
            int c0 = s0 + 8,  c1 = s0 + 9,  c2 = s0 + 10, c3 = s0 + 11;
            c0 = c0 > smax ? smax : c0;  c1 = c1 > smax ? smax : c1;
            c2 = c2 > smax ? smax : c2;  c3 = c3 > smax ? smax : c3;
            un0 = ub[(tbase + dir * c0) * Nn + lane];
            un1 = ub[(tbase + dir * c1) * Nn + lane];
            un2 = ub[(tbase + dir * c2) * Nn + lane];
            un3 = ub[(tbase + dir * c3) * Nn + lane];
        }
        wn0 = __expf(uq0); wn1 = __expf(uq1);
        wn2 = __expf(uq2); wn3 = __expf(uq3);

        #pragma unroll
        for (int k = 0; k < 4; ++k) {
            if (s0 + k >= trips) break;  // wave-uniform

            float wk = (k == 0) ? wq0 : (k == 1) ? wq1 : (k == 2) ? wq2 : wq3;

            // fwd: a' = (E^T a) * w   (w on output)
            // bwd: a' = E (w * a)     (w on input)
            float src = (w != 0) ? acc * wk : acc;

            // Depth-2 DPP ladder: all 16 xor masks.
            float t1 = dppf<0xB1>(src);    // xor1  quad_perm [1,0,3,2]
            float t2 = dppf<0x4E>(src);    // xor2  quad_perm [2,3,0,1]
            float t3 = dppf<0x1B>(src);    // xor3  quad_perm [3,2,1,0]
            float m7 = dppf<0x141>(src);   // xor7  row_half_mirror
            float m6 = dppf<0x141>(t1);    // xor6
            float m5 = dppf<0x141>(t2);    // xor5
            float m4 = dppf<0x141>(t3);    // xor4
            float r8  = dppf<0x128>(src);  // xor8  row_ror:8
            float r9  = dppf<0x128>(t1);   // xor9
            float r10 = dppf<0x128>(t2);   // xor10
            float r11 = dppf<0x128>(t3);   // xor11
            float r12 = dppf<0x128>(m4);   // xor12
            float r13 = dppf<0x128>(m5);   // xor13
            float r14 = dppf<0x128>(m6);   // xor14
            float r15 = dppf<0x128>(m7);   // xor15

            // gp[q] = (a at p^(2q), a at p^(2q+1)).
            f2 gp0 = {src, t1},  gp1 = {t2, t3};
            f2 gp2 = {m4, m5},   gp3 = {m6, m7};
            f2 gp4 = {r8, r9},   gp5 = {r10, r11};
            f2 gp6 = {r12, r13}, gp7 = {r14, r15};

            // Partials per output group g: even-q chain (aA), odd-q (aB).
            // EA{4g+h}.xy = (s=4h, 4h+1) -> gp[2h]; .zw = (4h+2,4h+3) -> gp[2h+1].
            f2 aA0 = gp0 * EA0.xy;  aA0 = gp2 * EA1.xy + aA0;
            aA0 = gp4 * EA2.xy + aA0;  aA0 = gp6 * EA3.xy + aA0;
            f2 aB0 = gp1 * EA0.zw;  aB0 = gp3 * EA1.zw + aB0;
            aB0 = gp5 * EA2.zw + aB0;  aB0 = gp7 * EA3.zw + aB0;

            f2 aA1 = gp0 * EA4.xy;  aA1 = gp2 * EA5.xy + aA1;
            aA1 = gp4 * EA6.xy + aA1;  aA1 = gp6 * EA7.xy + aA1;
            f2 aB1 = gp1 * EA4.zw;  aB1 = gp3 * EA5.zw + aB1;
            aB1 = gp5 * EA6.zw + aB1;  aB1 = gp7 * EA7.zw + aB1;

            f2 aA2 = gp0 * EA8.xy;  aA2 = gp2 * EA9.xy + aA2;
            aA2 = gp4 * EA10.xy + aA2;  aA2 = gp6 * EA11.xy + aA2;
            f2 aB2 = gp1 * EA8.zw;  aB2 = gp3 * EA9.zw + aB2;
            aB2 = gp5 * EA10.zw + aB2;  aB2 = gp7 * EA11.zw + aB2;

            f2 aA3 = gp0 * EA12.xy;  aA3 = gp2 * EA13.xy + aA3;
            aA3 = gp4 * EA14.xy + aA3;  aA3 = gp6 * EA15.xy + aA3;
            f2 aB3 = gp1 * EA12.zw;  aB3 = gp3 * EA13.zw + aB3;
            aB3 = gp5 * EA14.zw + aB3;  aB3 = gp7 * EA15.zw + aB3;

            // Cross-row reduce, all-VALU: bit5 (permlane32 pair-sum) then
            // bit4 (permlane16 pair-sum); replicated over 4-lane groups.
            f2 t0 = aA0 + aB0, u1 = aA1 + aB1;
            f2 u2 = aA2 + aB2, u3 = aA3 + aB3;
            float z0 = xsum16(xsum32(t0[0] + t0[1]));
            float z1 = xsum16(xsum32(u1[0] + u1[1]));
            float z2 = xsum16(xsum32(u2[0] + u2[1]));
            float z3 = xsum16(xsum32(u3[0] + u3[1]));
            // Keep the group with g == own row r (r bits: lane&16, lane&32).
            float zl = (lane & 16) ? z1 : z0;
            float zh = (lane & 16) ? z3 : z2;
            float z  = (lane & 32) ? zh : zl;

            acc = (w == 0) ? z * wk : z;
        }

        // Exact exponent-only rescale (once per 4 steps; keeps fp32 in
        // range: worst drift 4 steps * ~14 bits + ~10 bits lane spread).
        {
            unsigned s0b = (unsigned)__builtin_amdgcn_readfirstlane(
                (int)__float_as_uint(acc));
            int e = (int)((s0b >> 23) & 0xFF) - 127;
            off += e;
            acc *= __uint_as_float((unsigned)(127 - e) << 23);
        }

        wq0 = wn0; wq1 = wn1; wq2 = wn2; wq3 = wn3;
        uq0 = un0; uq1 = un1; uq2 = un2; uq3 = un3;
    }

    // Combine: out[b] = ln2 * (off_f + off_b + log2(sum_i a_i * b_i)).
    if (w == 1) {
        shb[lane] = acc;
        if (lane == 0) sh_off_b = off;
    }
    __syncthreads();
    if (w == 0) {
        float v = acc * shb[lane];
        float ssum = v;
        #pragma unroll
        for (int k = 32; k >= 1; k >>= 1)
            ssum += __shfl_xor(ssum, k, 64);
        if (lane == 0) {
            float l2 = __builtin_amdgcn_logf(ssum);  // v_log_f32 = log2
            out[b] = LN2 * ((float)(off + sh_off_b) + l2);
        }
    }
}

extern "C" void kernel_launch(void* const* d_in, const int* in_sizes, int n_in,
                              void* d_out, int out_size, void* d_ws, size_t ws_size,
                              hipStream_t stream) {
    const float* unary   = (const float*)d_in[0];
    const int*   lengths = (const int*)d_in[1];
    const float* trans   = (const float*)d_in[2];
    float*       out     = (float*)d_out;

    const int Bb = in_sizes[1];  // 512
    crf_fwd<<<Bb, 128, 0, stream>>>(unary, lengths, trans, out);
}

// Round 6
// 337.848 us; speedup vs baseline: 1.1035x; 1.1035x over previous
//
#include <hip/hip_runtime.h>

// CRF forward: B=512, T=1024, N=64. fwd/bwd split, one wave per chain.
// Round 16: HYBRID step = LDS row-gather + partial-output + tiny permlane
// reduce. Evidence from 5 body variants: LDS-gather broadcast (R10) =
// 708 cyc/step; ALL cross-lane-VALU-heavy bodies (readlane R11, DPP
// ladders R12-15) = ~1000 cyc/step regardless of composition -> on this
// chip the LDS pipe beats DPP/readlane for gathers, but R10 over-read
// (full 64-value vector per lane, 16xds_read_b128 = 16KiB/step/wave).
// Fix: partial-output decomposition. Lane (p=lane&15, r=lane>>4) computes
// P[g] = sum_{m<16} a[16r+m] * M[p+16g][16r+m]  (its own row slice only):
//   - ds_write_b32 new alpha, then 4x ds_read_b128 at a GROUP-UNIFORM
//     address (16 lanes same addr -> LDS broadcast, conflict-free); 4x
//     less LDS return traffic + 4x fewer DS ops than R10.
//   - 16 f4-FMAs vs resident named EA0..EA15 (residency pattern proven
//     in R14/15: Eperm staging -> contiguous f4 loads -> pin).
//   - reduce over r: xsum32+xsum16 permlane pair-sums (order-robust,
//     numerically verified in R15) -- only 8 cross-lane ops/step.
// Math (verified absmax 0.0 rounds 10/12-15): exp-domain recurrence
//   a'_j = (sum_i a_i E_ij) * w_j, exponent-only rescale every 4 steps,
//   out = ln2 * (off_f + off_b + log2(sum_i a_i b_i)).

typedef float f2 __attribute__((ext_vector_type(2)));
typedef float f4 __attribute__((ext_vector_type(4)));

constexpr int Tt = 1024;
constexpr int Nn = 64;
constexpr int ES  = 68;  // Erow stride (floats)
constexpr int EPS = 68;  // Eperm per-thread stride (floats), 272B
constexpr float LN2 = 0.69314718055994530942f;

// Pair-sum across the 32-lane halves (bit 5), order-robust: swap with a
// copy, add both outputs. s_nop 1 guards the VALU-write -> cross-lane-read
// hazard.
__device__ __forceinline__ float xsum32(float x) {
    float a = x, b = x;
    asm("s_nop 1\n\tv_permlane32_swap_b32 %0, %1" : "+v"(a), "+v"(b));
    return a + b;
}

// Pair-sum across 16-lane row pairs (bit 4), same order-robust pattern.
__device__ __forceinline__ float xsum16(float x) {
    float a = x, b = x;
    asm("s_nop 1\n\tv_permlane16_swap_b32 %0, %1" : "+v"(a), "+v"(b));
    return a + b;
}

__global__ __launch_bounds__(128, 1) void crf_fwd(
    const float* __restrict__ unary,
    const int*   __restrict__ lengths,
    const float* __restrict__ trans,
    float*       __restrict__ out)
{
    const int b    = blockIdx.x;
    const int tid  = threadIdx.x;
    const int w    = tid >> 6;   // 0 = forward wave, 1 = backward wave
    const int lane = tid & 63;
    const int p    = lane & 15;
    const int r    = lane >> 4;

    __shared__ float Erow[Nn * ES];     // Erow[i*ES+j] = exp(trans[i][j])
    __shared__ float Eperm[128 * EPS];  // per-thread E in gather order
    __shared__ __align__(16) float shp[2][Nn];  // per-wave alpha broadcast
    __shared__ float shb[Nn];           // beta at midpoint (combine)
    __shared__ int   sh_off_b;          // bwd exponent offset

    // Phase 1: stage E = exp(trans) row-major (coalesced global reads).
    #pragma unroll
    for (int c = 0; c < (Nn * Nn) / 128; ++c) {
        int idx = c * 128 + tid;
        Erow[(idx >> 6) * ES + (idx & 63)] = __expf(trans[idx]);
    }
    __syncthreads();

    // Phase 2: this thread's 64 E values in row-slice order:
    //   v = g*16 + m,  i = 16r + m,  o = p + 16g
    //   fwd: M[o][i] = E[i][o]  (a' = E^T a);  bwd: M[o][i] = E[o][i].
    float* ep = &Eperm[tid * EPS];
    #pragma unroll
    for (int v = 0; v < 64; ++v) {
        int g = v >> 4, m = v & 15;
        int i = 16 * r + m;
        int o = p + 16 * g;
        ep[v] = (w == 0) ? Erow[i * ES + o] : Erow[o * ES + i];
    }
    // Same-thread DS write->read is in-order; no barrier needed.

    // Phase 3: contiguous f4 loads into NAMED registers (residency pattern
    // proven in rounds 10/11/14/15), then pin.
    const f4* eb = (const f4*)ep;
    f4 EA0  = eb[0],  EA1  = eb[1],  EA2  = eb[2],  EA3  = eb[3];
    f4 EA4  = eb[4],  EA5  = eb[5],  EA6  = eb[6],  EA7  = eb[7];
    f4 EA8  = eb[8],  EA9  = eb[9],  EA10 = eb[10], EA11 = eb[11];
    f4 EA12 = eb[12], EA13 = eb[13], EA14 = eb[14], EA15 = eb[15];
    asm volatile("" : "+v"(EA0),  "+v"(EA1),  "+v"(EA2),  "+v"(EA3),
                      "+v"(EA4),  "+v"(EA5),  "+v"(EA6),  "+v"(EA7),
                      "+v"(EA8),  "+v"(EA9),  "+v"(EA10), "+v"(EA11),
                      "+v"(EA12), "+v"(EA13), "+v"(EA14), "+v"(EA15));

    int L = lengths[b];
    L = L < 1 ? 1 : (L > Tt ? Tt : L);
    const int m2 = (L - 1) >> 1;

    const float* ub = unary + (size_t)b * Tt * Nn;

    const int trips = (w == 0) ? m2 : (L - 1 - m2);
    const int tbase = (w == 0) ? 1 : (L - 1);
    const int dir   = (w == 0) ? 1 : -1;

    // Exp-domain state + exponent offset.
    float acc = (w == 0) ? __expf(ub[lane]) : 1.0f;
    int   off = 0;

    float* myp = shp[w];
    const f4* rowp = (const f4*)&shp[w][16 * r];  // group-uniform address

    // 8-step lookahead: wq = exp'd w for steps s0..s0+3,
    //                   uq = raw u for steps s0+4..s0+7.
    const int smax = trips > 0 ? trips - 1 : 0;
    float wq0, wq1, wq2, wq3, uq0, uq1, uq2, uq3;
    {
        int c0 = 0 < smax ? 0 : smax, c1 = 1 < smax ? 1 : smax;
        int c2 = 2 < smax ? 2 : smax, c3 = 3 < smax ? 3 : smax;
        wq0 = __expf(ub[(tbase + dir * c0) * Nn + lane]);
        wq1 = __expf(ub[(tbase + dir * c1) * Nn + lane]);
        wq2 = __expf(ub[(tbase + dir * c2) * Nn + lane]);
        wq3 = __expf(ub[(tbase + dir * c3) * Nn + lane]);
        int c4 = 4 < smax ? 4 : smax, c5 = 5 < smax ? 5 : smax;
        int c6 = 6 < smax ? 6 : smax, c7 = 7 < smax ? 7 : smax;
        uq0 = ub[(tbase + dir * c4) * Nn + lane];
        uq1 = ub[(tbase + dir * c5) * Nn + lane];
        uq2 = ub[(tbase + dir * c6) * Nn + lane];
        uq3 = ub[(tbase + dir * c7) * Nn + lane];
    }

    for (int s0 = 0; s0 < trips; s0 += 4) {
        // Issue raw loads 8 ahead; exp the 4-ahead batch. Both off-chain.
        float un0, un1, un2, un3, wn0, wn1, wn2, wn3;
        {
            int c0 = s0 + 8,  c1 = s0 + 9,  c2 = s0 + 10, c3 = s0 + 11;
            c0 = c0 > smax ? smax : c0;  c1 = c1 > smax ? smax : c1;
            c2 = c2 > smax ? smax : c2;  c3 = c3 > smax ? smax : c3;
            un0 = ub[(tbase + dir * c0) * Nn + lane];
            un1 = ub[(tbase + dir * c1) * Nn + lane];
            un2 = ub[(tbase + dir * c2) * Nn + lane];
            un3 = ub[(tbase + dir * c3) * Nn + lane];
        }
        wn0 = __expf(uq0); wn1 = __expf(uq1);
        wn2 = __expf(uq2); wn3 = __expf(uq3);

        #pragma unroll
        for (int k = 0; k < 4; ++k) {
            if (s0 + k >= trips) break;  // wave-uniform

            float wk = (k == 0) ? wq0 : (k == 1) ? wq1 : (k == 2) ? wq2 : wq3;

            // fwd: a' = (E^T a) * w   (w on output)
            // bwd: a' = E (w * a)     (w on input)
            float src = (w != 0) ? acc * wk : acc;

            // Publish alpha; read own row slice (4x b128, group-uniform
            // address -> LDS broadcast). Same-wave DS ops are in-order.
            myp[lane] = src;
            f4 av0 = rowp[0], av1 = rowp[1], av2 = rowp[2], av3 = rowp[3];

            // Partials P[g] = <a_row, M-row-slice>, f4 chains depth 4.
            f4 A0 = av0 * EA0;   A0 = av1 * EA1  + A0;
            A0 = av2 * EA2 + A0; A0 = av3 * EA3  + A0;
            f4 A1 = av0 * EA4;   A1 = av1 * EA5  + A1;
            A1 = av2 * EA6 + A1; A1 = av3 * EA7  + A1;
            f4 A2 = av0 * EA8;   A2 = av1 * EA9  + A2;
            A2 = av2 * EA10 + A2; A2 = av3 * EA11 + A2;
            f4 A3 = av0 * EA12;  A3 = av1 * EA13 + A3;
            A3 = av2 * EA14 + A3; A3 = av3 * EA15 + A3;

            // Horizontal sums -> per-lane scalars.
            f2 h0 = A0.xy + A0.zw, h1 = A1.xy + A1.zw;
            f2 h2 = A2.xy + A2.zw, h3 = A3.xy + A3.zw;
            float p0 = h0[0] + h0[1], p1 = h1[0] + h1[1];
            float p2 = h2[0] + h2[1], p3 = h3[0] + h3[1];

            // Reduce over row groups r (bits 5 then 4), replicated.
            float z0 = xsum16(xsum32(p0));
            float z1 = xsum16(xsum32(p1));
            float z2 = xsum16(xsum32(p2));
            float z3 = xsum16(xsum32(p3));
            // Keep the group with g == own row r (r bits: lane&16, lane&32).
            float zl = (lane & 16) ? z1 : z0;
            float zh = (lane & 16) ? z3 : z2;
            float z  = (lane & 32) ? zh : zl;

            acc = (w == 0) ? z * wk : z;
        }

        // Exact exponent-only rescale (once per 4 steps; keeps fp32 in
        // range: worst drift 4 steps * ~14 bits + ~10 bits lane spread).
        {
            unsigned s0b = (unsigned)__builtin_amdgcn_readfirstlane(
                (int)__float_as_uint(acc));
            int e = (int)((s0b >> 23) & 0xFF) - 127;
            off += e;
            acc *= __uint_as_float((unsigned)(127 - e) << 23);
        }

        wq0 = wn0; wq1 = wn1; wq2 = wn2; wq3 = wn3;
        uq0 = un0; uq1 = un1; uq2 = un2; uq3 = un3;
    }

    // Combine: out[b] = ln2 * (off_f + off_b + log2(sum_i a_i * b_i)).
    if (w == 1) {
        shb[lane] = acc;
        if (lane == 0) sh_off_b = off;
    }
    __syncthreads();
    if (w == 0) {
        float v = acc * shb[lane];
        float ssum = v;
        #pragma unroll
        for (int k = 32; k >= 1; k >>= 1)
            ssum += __shfl_xor(ssum, k, 64);
        if (lane == 0) {
            float l2 = __builtin_amdgcn_logf(ssum);  // v_log_f32 = log2
            out[b] = LN2 * ((float)(off + sh_off_b) + l2);
        }
    }
}

extern "C" void kernel_launch(void* const* d_in, const int* in_sizes, int n_in,
                              void* d_out, int out_size, void* d_ws, size_t ws_size,
                              hipStream_t stream) {
    const float* unary   = (const float*)d_in[0];
    const int*   lengths = (const int*)d_in[1];
    const float* trans   = (const float*)d_in[2];
    float*       out     = (float*)d_out;

    const int Bb = in_sizes[1];  // 512
    crf_fwd<<<Bb, 128, 0, stream>>>(unary, lengths, trans, out);
}

// Round 7
// 295.443 us; speedup vs baseline: 1.2619x; 1.1435x over previous
//
#include <hip/hip_runtime.h>

// CRF forward: B=512, T=1024, N=64. fwd/bwd split, one wave per chain.
// Round 17: P=2 HALF-SPLIT step — balance LDS traffic vs reduce depth.
// Calibration from R10-R16:
//   R10 (P=1): 16x ds_read_b128/wave/step, no cross-lane -> LDS-throughput
//     bound: 16x12cyc x4 waves/CU = 768 cyc/CU/step ~= measured 709. 151us.
//   R16 (P=4): 4x b128 but 8 dependent permlane stages -> chain-bound
//     ~907 cyc/step. 193us. Permlane reduce stages are empirically ~3x
//     costlier than naive count; LDS throughput cost is invariant to
//     block scheduling, so only traffic reduction helps it.
// P=2: lane L (h=L>>5, q=L&31) computes partials for outputs {q, q+32}
// over inputs i in [32h, 32h+32):
//   - 8x ds_read_b128 from &shp[w][32h] (2 distinct addrs/instr -> 2-way
//     broadcast, free per bank rules). LDS term: 8x12x4 = 400 cyc/CU.
//   - 16 f4-FMAs vs resident named EA0..EA15 (residency proven R14-16).
//   - reduce: ONE xsum32 per output (2 swaps, depth 1) + 1 select.
// Math (verified absmax 0.0 rounds 10/12-16): exp-domain recurrence
//   a'_j = (sum_i a_i E_ij) * w_j, exponent-only rescale every 4 steps,
//   out = ln2 * (off_f + off_b + log2(sum_i a_i b_i)).

typedef float f2 __attribute__((ext_vector_type(2)));
typedef float f4 __attribute__((ext_vector_type(4)));

constexpr int Tt = 1024;
constexpr int Nn = 64;
constexpr int ES  = 68;  // Erow stride (floats)
constexpr int EPS = 68;  // Eperm per-thread stride (floats), 272B
constexpr float LN2 = 0.69314718055994530942f;

// Pair-sum across the 32-lane halves (bit 5), order-robust: swap with a
// copy, add both outputs. s_nop 1 guards the VALU-write -> cross-lane-read
// hazard.
__device__ __forceinline__ float xsum32(float x) {
    float a = x, b = x;
    asm("s_nop 1\n\tv_permlane32_swap_b32 %0, %1" : "+v"(a), "+v"(b));
    return a + b;
}

__global__ __launch_bounds__(128, 1) void crf_fwd(
    const float* __restrict__ unary,
    const int*   __restrict__ lengths,
    const float* __restrict__ trans,
    float*       __restrict__ out)
{
    const int b    = blockIdx.x;
    const int tid  = threadIdx.x;
    const int w    = tid >> 6;   // 0 = forward wave, 1 = backward wave
    const int lane = tid & 63;
    const int q    = lane & 31;  // output index low bits
    const int h    = lane >> 5;  // input half

    __shared__ float Erow[Nn * ES];     // Erow[i*ES+j] = exp(trans[i][j])
    __shared__ float Eperm[128 * EPS];  // per-thread E in gather order
    __shared__ __align__(16) float shp[2][Nn];  // per-wave alpha broadcast
    __shared__ float shb[Nn];           // beta at midpoint (combine)
    __shared__ int   sh_off_b;          // bwd exponent offset

    // Phase 1: stage E = exp(trans) row-major (coalesced global reads).
    #pragma unroll
    for (int c = 0; c < (Nn * Nn) / 128; ++c) {
        int idx = c * 128 + tid;
        Erow[(idx >> 6) * ES + (idx & 63)] = __expf(trans[idx]);
    }
    __syncthreads();

    // Phase 2: this thread's 64 E values in half-slice order:
    //   v<32:  o = q,     i = 32h + v        (slot A)
    //   v>=32: o = q+32,  i = 32h + (v-32)   (slot B)
    //   fwd: M[o][i] = E[i][o]  (a' = E^T a);  bwd: M[o][i] = E[o][i].
    float* ep = &Eperm[tid * EPS];
    #pragma unroll
    for (int v = 0; v < 64; ++v) {
        int o = q + 32 * (v >> 5);
        int i = 32 * h + (v & 31);
        ep[v] = (w == 0) ? Erow[i * ES + o] : Erow[o * ES + i];
    }
    // Same-thread DS write->read is in-order; no barrier needed.

    // Phase 3: contiguous f4 loads into NAMED registers (residency pattern
    // proven in rounds 10/11/14/15/16), then pin.
    const f4* eb = (const f4*)ep;
    f4 EA0  = eb[0],  EA1  = eb[1],  EA2  = eb[2],  EA3  = eb[3];
    f4 EA4  = eb[4],  EA5  = eb[5],  EA6  = eb[6],  EA7  = eb[7];
    f4 EA8  = eb[8],  EA9  = eb[9],  EA10 = eb[10], EA11 = eb[11];
    f4 EA12 = eb[12], EA13 = eb[13], EA14 = eb[14], EA15 = eb[15];
    asm volatile("" : "+v"(EA0),  "+v"(EA1),  "+v"(EA2),  "+v"(EA3),
                      "+v"(EA4),  "+v"(EA5),  "+v"(EA6),  "+v"(EA7),
                      "+v"(EA8),  "+v"(EA9),  "+v"(EA10), "+v"(EA11),
                      "+v"(EA12), "+v"(EA13), "+v"(EA14), "+v"(EA15));

    int L = lengths[b];
    L = L < 1 ? 1 : (L > Tt ? Tt : L);
    const int m2 = (L - 1) >> 1;

    const float* ub = unary + (size_t)b * Tt * Nn;

    const int trips = (w == 0) ? m2 : (L - 1 - m2);
    const int tbase = (w == 0) ? 1 : (L - 1);
    const int dir   = (w == 0) ? 1 : -1;

    // Exp-domain state + exponent offset.
    float acc = (w == 0) ? __expf(ub[lane]) : 1.0f;
    int   off = 0;

    float* myp = shp[w];
    const f4* rowp = (const f4*)&shp[w][32 * h];  // half-uniform address

    // 8-step lookahead: wq* = exp'd w for steps s0..s0+3,
    //                   uq* = raw u for steps s0+4..s0+7.
    const int smax = trips > 0 ? trips - 1 : 0;
    float wq0, wq1, wq2, wq3, uq0, uq1, uq2, uq3;
    {
        int c0 = 0 < smax ? 0 : smax, c1 = 1 < smax ? 1 : smax;
        int c2 = 2 < smax ? 2 : smax, c3 = 3 < smax ? 3 : smax;
        wq0 = __expf(ub[(tbase + dir * c0) * Nn + lane]);
        wq1 = __expf(ub[(tbase + dir * c1) * Nn + lane]);
        wq2 = __expf(ub[(tbase + dir * c2) * Nn + lane]);
        wq3 = __expf(ub[(tbase + dir * c3) * Nn + lane]);
        int c4 = 4 < smax ? 4 : smax, c5 = 5 < smax ? 5 : smax;
        int c6 = 6 < smax ? 6 : smax, c7 = 7 < smax ? 7 : smax;
        uq0 = ub[(tbase + dir * c4) * Nn + lane];
        uq1 = ub[(tbase + dir * c5) * Nn + lane];
        uq2 = ub[(tbase + dir * c6) * Nn + lane];
        uq3 = ub[(tbase + dir * c7) * Nn + lane];
    }

    for (int s0 = 0; s0 < trips; s0 += 4) {
        // Issue raw loads 8 ahead; exp the 4-ahead batch. Both off-chain.
        float un0, un1, un2, un3, wn0, wn1, wn2, wn3;
        {
            int c0 = s0 + 8,  c1 = s0 + 9,  c2 = s0 + 10, c3 = s0 + 11;
            c0 = c0 > smax ? smax : c0;  c1 = c1 > smax ? smax : c1;
            c2 = c2 > smax ? smax : c2;  c3 = c3 > smax ? smax : c3;
            un0 = ub[(tbase + dir * c0) * Nn + lane];
            un1 = ub[(tbase + dir * c1) * Nn + lane];
            un2 = ub[(tbase + dir * c2) * Nn + lane];
            un3 = ub[(tbase + dir * c3) * Nn + lane];
        }
        wn0 = __expf(uq0); wn1 = __expf(uq1);
        wn2 = __expf(uq2); wn3 = __expf(uq3);

        #pragma unroll
        for (int k = 0; k < 4; ++k) {
            if (s0 + k >= trips) break;  // wave-uniform

            float wk = (k == 0) ? wq0 : (k == 1) ? wq1 : (k == 2) ? wq2 : wq3;

            // fwd: a' = (E^T a) * w   (w on output)
            // bwd: a' = E (w * a)     (w on input)
            float src = (w != 0) ? acc * wk : acc;

            // Publish alpha; read own input half (8x b128, 2 distinct
            // addresses per instr -> broadcast). Same-wave DS in-order.
            myp[lane] = src;
            f4 av0 = rowp[0], av1 = rowp[1], av2 = rowp[2], av3 = rowp[3];
            f4 av4 = rowp[4], av5 = rowp[5], av6 = rowp[6], av7 = rowp[7];

            // Partials: Pa = <half, M[q][half]>, Pb = <half, M[q+32][half]>.
            // Two interleaved chains each for ILP.
            f4 Aa = av0 * EA0;       f4 Ab = av1 * EA1;
            Aa = av2 * EA2 + Aa;     Ab = av3 * EA3 + Ab;
            Aa = av4 * EA4 + Aa;     Ab = av5 * EA5 + Ab;
            Aa = av6 * EA6 + Aa;     Ab = av7 * EA7 + Ab;
            f4 Ba = av0 * EA8;       f4 Bb = av1 * EA9;
            Ba = av2 * EA10 + Ba;    Bb = av3 * EA11 + Bb;
            Ba = av4 * EA12 + Ba;    Bb = av5 * EA13 + Bb;
            Ba = av6 * EA14 + Ba;    Bb = av7 * EA15 + Bb;

            f4 At = Aa + Ab;         f4 Bt = Ba + Bb;
            f2 Ah = At.xy + At.zw;   f2 Bh = Bt.xy + Bt.zw;
            float Pa = Ah[0] + Ah[1];
            float Pb = Bh[0] + Bh[1];

            // Cross-half reduce: one permlane32 pair-sum per output.
            float za = xsum32(Pa);   // out[q],    replicated both halves
            float zb = xsum32(Pb);   // out[q+32], replicated both halves
            float z  = (lane & 32) ? zb : za;

            acc = (w == 0) ? z * wk : z;
        }

        // Exact exponent-only rescale (once per 4 steps; keeps fp32 in
        // range: worst drift 4 steps * ~14 bits + ~10 bits lane spread).
        {
            unsigned s0b = (unsigned)__builtin_amdgcn_readfirstlane(
                (int)__float_as_uint(acc));
            int e = (int)((s0b >> 23) & 0xFF) - 127;
            off += e;
            acc *= __uint_as_float((unsigned)(127 - e) << 23);
        }

        wq0 = wn0; wq1 = wn1; wq2 = wn2; wq3 = wn3;
        uq0 = un0; uq1 = un1; uq2 = un2; uq3 = un3;
    }

    // Combine: out[b] = ln2 * (off_f + off_b + log2(sum_i a_i * b_i)).
    if (w == 1) {
        shb[lane] = acc;
        if (lane == 0) sh_off_b = off;
    }
    __syncthreads();
    if (w == 0) {
        float v = acc * shb[lane];
        float ssum = v;
        #pragma unroll
        for (int k = 32; k >= 1; k >>= 1)
            ssum += __shfl_xor(ssum, k, 64);
        if (lane == 0) {
            float l2 = __builtin_amdgcn_logf(ssum);  // v_log_f32 = log2
            out[b] = LN2 * ((float)(off + sh_off_b) + l2);
        }
    }
}

extern "C" void kernel_launch(void* const* d_in, const int* in_sizes, int n_in,
                              void* d_out, int out_size, void* d_ws, size_t ws_size,
                              hipStream_t stream) {
    const float* unary   = (const float*)d_in[0];
    const int*   lengths = (const int*)d_in[1];
    const float* trans   = (const float*)d_in[2];
    float*       out     = (float*)d_out;

    const int Bb = in_sizes[1];  // 512
    crf_fwd<<<Bb, 128, 0, stream>>>(unary, lengths, trans, out);
}